// Round 25
// baseline (208.560 us; speedup 1.0000x reference)
//
#include <hip/hip_runtime.h>

// FP8 MLP, fully fused:  out = q(relu(q(x)@q(w1)^T)) @ q(w2)^T
// R25 = R21 (166us stable x3) + SUPER-STEP PIPELINING: K-tiles processed in
// pairs. Per super-step: prefetch BOTH next tiles (8 w1 global loads + 8 B
// ds_reads), then a contiguous 32-MFMA burst. Rationale: at 2 waves/SIMD the
// residue is both-waves-in-load-phase matrix-pipe starvation; halving load-
// segment frequency quadratically cuts the overlap probability. NKS=13 ->
// 6 paired + 1 single step per chunk, prefetch chains across chunks.
// Registers: 4 operand sets (128) + b2v(16) + addr(~25) arch + 64 AGPR acc
// ~= 233 < 256 unified cap at 1 block/CU (LDS-bound occupancy; the R16/R19/
// R22 spill lesson applied: this ONLY fits at 1 block/CU).

typedef float f32x4 __attribute__((ext_vector_type(4)));
typedef float f32x16 __attribute__((ext_vector_type(16)));

#define DIN 784
#define KP  832          // 13 * 64 (zero-padded K)
#define DH  4096
#define NKS 13
#define NCH 16
#define CHUNK 256
#define MROWS 128

__device__ __forceinline__ unsigned long long q8(float4 a, float4 b) {
  int lo = __builtin_amdgcn_cvt_pk_fp8_f32(a.x, a.y, 0, false);
  lo     = __builtin_amdgcn_cvt_pk_fp8_f32(a.z, a.w, lo, true);
  int hi = __builtin_amdgcn_cvt_pk_fp8_f32(b.x, b.y, 0, false);
  hi     = __builtin_amdgcn_cvt_pk_fp8_f32(b.z, b.w, hi, true);
  return (unsigned long long)(unsigned)lo |
         ((unsigned long long)(unsigned)hi << 32);
}

__device__ __forceinline__ f32x16 zero16() { f32x16 z = {}; return z; }

// ---- w1 quantize: f32 [4096][784] -> fp8, wave-coalesced blocked layout ----
// 16KB block (nch*13+ks). Within: slice=(n>>6)&3 (4KB = 64 dh rows),
// sub-block (tq*2+ai) (1KB; tq=k-half, ai=row-32-group), lane=(hi2*32+l31)*16.
// 16B content: va=q8(w1[n][ks*64+(q&1)*32+(q>>1)*8..+8]), vb = same +16.

__global__ __launch_bounds__(256) void quant_w1_k(const float* __restrict__ w1,
                                                  unsigned char* __restrict__ w1qb) {
  int idx = blockIdx.x * 256 + threadIdx.x;       // 4096 n * 52 groups
  int n = idx / 52, g = idx % 52;
  int ks = g >> 2, q = g & 3;
  int kA = ks * 64 + (q & 1) * 32 + (q >> 1) * 8;
  int kB = kA + 16;
  const float* r = w1 + (size_t)n * DIN;
  unsigned long long va = 0ull, vb = 0ull;
  if (kA < DIN) va = q8(*(const float4*)(r + kA), *(const float4*)(r + kA + 4));
  if (kB < DIN) vb = q8(*(const float4*)(r + kB), *(const float4*)(r + kB + 4));
  ulonglong2 v; v.x = va; v.y = vb;
  int slice = (n >> 6) & 3, rr = n & 63, ai = rr >> 5, l31n = rr & 31;
  int hi2 = q >> 1, tq = q & 1;
  size_t off = ((size_t)((n >> 8) * NKS + ks) << 14) + slice * 4096 +
               (tq * 2 + ai) * 1024 + (hi2 * 32 + l31n) * 16;
  *(ulonglong2*)(w1qb + off) = v;
}

__global__ __launch_bounds__(256) void quant_w2_k(const float* __restrict__ w2,
                                                  unsigned char* __restrict__ w2q) {
  int idx = blockIdx.x * 256 + threadIdx.x;       // 16 rows * 256 chunks(16B)
  int r = idx >> 8, c = idx & 255;
  ulonglong2 v; v.x = 0ull; v.y = 0ull;
  if (r < 10) {
    const float* p = w2 + (size_t)r * DH + c * 16;
    v.x = q8(*(const float4*)(p), *(const float4*)(p + 4));
    v.y = q8(*(const float4*)(p + 8), *(const float4*)(p + 12));
  }
  *(ulonglong2*)(w2q + (size_t)r * DH + c * 16) = v;  // rows 10..15 = 0
}

// ------------------------------ fused MLP -----------------------------------

__global__ __launch_bounds__(512, 1)
void fused_mlp(const float* __restrict__ x,
               const unsigned char* __restrict__ w1qb,
               const unsigned char* __restrict__ w2q,
               float* __restrict__ out) {
  __shared__ unsigned char A[NKS * MROWS * 64];   // 104 KB x-panel, read-only
  __shared__ unsigned char H[MROWS * CHUNK];      // 32 KB

  const int tid = threadIdx.x;
  const int lane = tid & 63;
  const int w  = tid >> 6;          // wave 0..7
  const int l31 = lane & 31;
  const int hi  = lane >> 5;
  const int wdi = w >> 1;           // dh 64-slice (0..3) of the 256-chunk
  const int wbi = w & 1;            // batch 64-half
  const long row0 = (long)blockIdx.x * MROWS;

  // ---- prologue: quantize 128 x-rows into the LDS panel ----
  for (int it = 0; it < 13; ++it) {
    int idx = tid + it * 512;                     // 13*128*4 = 6656 exactly
    int ks = idx >> 9, rem = idx & 511, row = rem >> 2, q = rem & 3;
    int kA = ks * 64 + (q & 1) * 32 + (q >> 1) * 8;
    int kB = kA + 16;
    const float* xr = x + (row0 + row) * DIN;
    unsigned long long va = 0ull, vb = 0ull;
    if (kA < DIN) va = q8(*(const float4*)(xr + kA), *(const float4*)(xr + kA + 4));
    if (kB < DIN) vb = q8(*(const float4*)(xr + kB), *(const float4*)(xr + kB + 4));
    ulonglong2 v; v.x = va; v.y = vb;
    int slot = q ^ ((row >> 2) & 3);              // conflict-free involution
    *(ulonglong2*)&A[ks * 8192 + row * 64 + slot * 16] = v;
  }
  __syncthreads();   // panel ready

  // loop-invariant offsets
  const int br0 = wbi * 64 + l31, br1 = br0 + 32;           // x batch rows
#define SOFF(r_, g_) ((r_) * 64 + ((((g_) ^ (((r_) >> 2) & 3))) << 4))
  const unsigned char* aX0 = &A[SOFF(br0, 2 * hi)];
  const unsigned char* aX1 = &A[SOFF(br0, 2 * hi + 1)];
  const unsigned char* aX2 = &A[SOFF(br1, 2 * hi)];
  const unsigned char* aX3 = &A[SOFF(br1, 2 * hi + 1)];
#undef SOFF
  const int r2 = w * 16 + (lane & 15);                      // fc2 batch row
  const int x2 = (lane & 15) << 1;
  const int dh0 = wdi * 64 + 4 * hi;                        // H-write dh bases
  const int dh1 = dh0 + 32;
  const unsigned char* w2p0 = w2q + (size_t)(lane & 15) * DH + (lane >> 4) * 8;
  const unsigned char* wptr = w1qb + wdi * 4096 + (size_t)lane * 16;

  // current super-step operands: steps (s0: cw0..3/cb0..3, s1: cw4..7/cb4..7)
  ulonglong2 cw0, cw1, cw2, cw3, cw4, cw5, cw6, cw7;
  ulonglong2 cb0, cb1, cb2, cb3, cb4, cb5, cb6, cb7;
  ulonglong2 nw0, nw1, nw2, nw3, nw4, nw5, nw6, nw7;
  ulonglong2 nb0, nb1, nb2, nb3, nb4, nb5, nb6, nb7;

  // load S0 of chunk 0 (ks = 0,1)
  cw0 = *(const ulonglong2*)(wptr);
  cw1 = *(const ulonglong2*)(wptr + 1024);
  cw2 = *(const ulonglong2*)(wptr + 2048);
  cw3 = *(const ulonglong2*)(wptr + 3072);
  cw4 = *(const ulonglong2*)(wptr + (1 << 14));
  cw5 = *(const ulonglong2*)(wptr + (1 << 14) + 1024);
  cw6 = *(const ulonglong2*)(wptr + (1 << 14) + 2048);
  cw7 = *(const ulonglong2*)(wptr + (1 << 14) + 3072);
  cb0 = *(const ulonglong2*)(aX0);
  cb1 = *(const ulonglong2*)(aX1);
  cb2 = *(const ulonglong2*)(aX2);
  cb3 = *(const ulonglong2*)(aX3);
  cb4 = *(const ulonglong2*)(aX0 + 8192);
  cb5 = *(const ulonglong2*)(aX1 + 8192);
  cb6 = *(const ulonglong2*)(aX2 + 8192);
  cb7 = *(const ulonglong2*)(aX3 + 8192);
  nw4 = cw4; nw5 = cw5; nw6 = cw6; nw7 = cw7;   // init (avoid uninit paths)
  nb4 = cb4; nb5 = cb5; nb6 = cb6; nb7 = cb7;

#define MFMA_(A_, B_, C_) \
  C_ = __builtin_amdgcn_mfma_f32_32x32x16_fp8_fp8((long)(A_), (long)(B_), C_, 0, 0, 0)
#define STEP(W0, W1, W2, W3, B0, B1, B2, B3)                                   \
  do {                                                                         \
    MFMA_(W0.x, B0.x, c00); MFMA_(W0.x, B2.x, c01);                            \
    MFMA_(W1.x, B0.x, c10); MFMA_(W1.x, B2.x, c11);                            \
    MFMA_(W0.y, B0.y, c00); MFMA_(W0.y, B2.y, c01);                            \
    MFMA_(W1.y, B0.y, c10); MFMA_(W1.y, B2.y, c11);                            \
    MFMA_(W2.x, B1.x, c00); MFMA_(W2.x, B3.x, c01);                            \
    MFMA_(W3.x, B1.x, c10); MFMA_(W3.x, B3.x, c11);                            \
    MFMA_(W2.y, B1.y, c00); MFMA_(W2.y, B3.y, c01);                            \
    MFMA_(W3.y, B1.y, c10); MFMA_(W3.y, B3.y, c11);                            \
  } while (0)

  f32x4 acc2 = {0.f, 0.f, 0.f, 0.f};

#pragma unroll 1
  for (int nch = 0; nch < NCH; ++nch) {
    // hoist fc2 w2 fragments for this chunk
    long b2v[8];
#pragma unroll
    for (int kk = 0; kk < 8; ++kk)
      b2v[kk] = *(const long long*)(w2p0 + nch * CHUNK + kk * 32);

    f32x16 c00 = zero16(), c01 = zero16(), c10 = zero16(), c11 = zero16();

    // 7 super-steps: sp 0..5 = K-tile pairs (2sp, 2sp+1); sp 6 = single ks=12
#pragma unroll
    for (int sp = 0; sp < 7; ++sp) {
      if (sp < 5) {
        const unsigned char* pa = wptr + ((size_t)(2 * sp + 2) << 14);
        const unsigned char* pb = wptr + ((size_t)(2 * sp + 3) << 14);
        nw0 = *(const ulonglong2*)(pa);
        nw1 = *(const ulonglong2*)(pa + 1024);
        nw2 = *(const ulonglong2*)(pa + 2048);
        nw3 = *(const ulonglong2*)(pa + 3072);
        nw4 = *(const ulonglong2*)(pb);
        nw5 = *(const ulonglong2*)(pb + 1024);
        nw6 = *(const ulonglong2*)(pb + 2048);
        nw7 = *(const ulonglong2*)(pb + 3072);
        nb0 = *(const ulonglong2*)(aX0 + (2 * sp + 2) * 8192);
        nb1 = *(const ulonglong2*)(aX1 + (2 * sp + 2) * 8192);
        nb2 = *(const ulonglong2*)(aX2 + (2 * sp + 2) * 8192);
        nb3 = *(const ulonglong2*)(aX3 + (2 * sp + 2) * 8192);
        nb4 = *(const ulonglong2*)(aX0 + (2 * sp + 3) * 8192);
        nb5 = *(const ulonglong2*)(aX1 + (2 * sp + 3) * 8192);
        nb6 = *(const ulonglong2*)(aX2 + (2 * sp + 3) * 8192);
        nb7 = *(const ulonglong2*)(aX3 + (2 * sp + 3) * 8192);
      } else if (sp == 5) {
        // next = single step ks = 12
        const unsigned char* pa = wptr + ((size_t)12 << 14);
        nw0 = *(const ulonglong2*)(pa);
        nw1 = *(const ulonglong2*)(pa + 1024);
        nw2 = *(const ulonglong2*)(pa + 2048);
        nw3 = *(const ulonglong2*)(pa + 3072);
        nb0 = *(const ulonglong2*)(aX0 + 12 * 8192);
        nb1 = *(const ulonglong2*)(aX1 + 12 * 8192);
        nb2 = *(const ulonglong2*)(aX2 + 12 * 8192);
        nb3 = *(const ulonglong2*)(aX3 + 12 * 8192);
      } else if (nch < NCH - 1) {
        // next = next chunk's S0 (ks 0,1)
        const unsigned char* pa = wptr + ((size_t)NKS << 14);
        const unsigned char* pb = pa + (1 << 14);
        nw0 = *(const ulonglong2*)(pa);
        nw1 = *(const ulonglong2*)(pa + 1024);
        nw2 = *(const ulonglong2*)(pa + 2048);
        nw3 = *(const ulonglong2*)(pa + 3072);
        nw4 = *(const ulonglong2*)(pb);
        nw5 = *(const ulonglong2*)(pb + 1024);
        nw6 = *(const ulonglong2*)(pb + 2048);
        nw7 = *(const ulonglong2*)(pb + 3072);
        nb0 = *(const ulonglong2*)(aX0);
        nb1 = *(const ulonglong2*)(aX1);
        nb2 = *(const ulonglong2*)(aX2);
        nb3 = *(const ulonglong2*)(aX3);
        nb4 = *(const ulonglong2*)(aX0 + 8192);
        nb5 = *(const ulonglong2*)(aX1 + 8192);
        nb6 = *(const ulonglong2*)(aX2 + 8192);
        nb7 = *(const ulonglong2*)(aX3 + 8192);
      }

      __builtin_amdgcn_s_setprio(1);
      STEP(cw0, cw1, cw2, cw3, cb0, cb1, cb2, cb3);
      if (sp < 6) STEP(cw4, cw5, cw6, cw7, cb4, cb5, cb6, cb7);
      __builtin_amdgcn_s_setprio(0);

      cw0 = nw0; cw1 = nw1; cw2 = nw2; cw3 = nw3;
      cw4 = nw4; cw5 = nw5; cw6 = nw6; cw7 = nw7;
      cb0 = nb0; cb1 = nb1; cb2 = nb2; cb3 = nb3;
      cb4 = nb4; cb5 = nb5; cb6 = nb6; cb7 = nb7;
    }
    wptr += (size_t)NKS << 14;

    // ---- relu + quantize -> H (dh-in-frag = (reg&3) + 8*(reg>>2) + 4*hi) ----
#define HWR(accv, rbv, dhb)                                                    \
    do {                                                                       \
      _Pragma("unroll") for (int qq = 0; qq < 4; ++qq) {                       \
        int dh_ = (dhb) + 8 * qq;                                              \
        unsigned wv = (unsigned)__builtin_amdgcn_cvt_pk_fp8_f32(               \
            fmaxf((accv)[4*qq+0], 0.f), fmaxf((accv)[4*qq+1], 0.f), 0, false); \
        wv = (unsigned)__builtin_amdgcn_cvt_pk_fp8_f32(                        \
            fmaxf((accv)[4*qq+2], 0.f), fmaxf((accv)[4*qq+3], 0.f), (int)wv, true); \
        int sp_ = (dh_ >> 2) ^ (((rbv) & 15) << 1);                            \
        *(unsigned int*)&H[(rbv) * CHUNK + sp_ * 4] = wv;                      \
      }                                                                        \
    } while (0)
    HWR(c00, br0, dh0);
    HWR(c01, br1, dh0);
    HWR(c10, br0, dh1);
    HWR(c11, br1, dh1);
#undef HWR
    asm volatile("s_waitcnt lgkmcnt(0)" ::: "memory");
    __builtin_amdgcn_s_barrier();
    asm volatile("" ::: "memory");
    // ---- fc2: 8 MFMAs (16x16x32), wave w -> rows w*16..w*16+15, full 256k ----
#pragma unroll
    for (int kk = 0; kk < 8; ++kk) {
      int dhl = kk * 32 + (lane >> 4) * 8;
      long a2 = *(const long long*)&H[r2 * CHUNK + (((dhl >> 2) ^ x2) << 2)];
      acc2 = __builtin_amdgcn_mfma_f32_16x16x32_fp8_fp8(a2, b2v[kk], acc2, 0, 0, 0);
    }
    asm volatile("s_waitcnt lgkmcnt(0)" ::: "memory");
    __builtin_amdgcn_s_barrier();   // H reads done before next chunk's writes
    asm volatile("" ::: "memory");
  }
#undef STEP
#undef MFMA_

  // ---- store out[128][10]: wave w rows w*16.., col = lane&15 ----
  if ((lane & 15) < 10) {
#pragma unroll
    for (int j = 0; j < 4; ++j) {
      int rl = w * 16 + (lane >> 4) * 4 + j;
      out[(row0 + rl) * 10 + (lane & 15)] = acc2[j];
    }
  }
}

extern "C" void kernel_launch(void* const* d_in, const int* in_sizes, int n_in,
                              void* d_out, int out_size, void* d_ws, size_t ws_size,
                              hipStream_t stream) {
  const float* x  = (const float*)d_in[0];
  const float* w1 = (const float*)d_in[1];
  const float* w2 = (const float*)d_in[2];
  float* out = (float*)d_out;

  unsigned char* w1qb = (unsigned char*)d_ws;             // blocked, 3.4MB
  unsigned char* w2q  = w1qb + (size_t)DH * KP;           // [16][4096]

  quant_w1_k<<<(DH * 52) / 256, 256, 0, stream>>>(w1, w1qb);
  quant_w2_k<<<16, 256, 0, stream>>>(w2, w2q);
  fused_mlp<<<32768 / MROWS, 512, 0, stream>>>(x, w1qb, w2q, out);
}